// Round 6
// baseline (232.848 us; speedup 1.0000x reference)
//
#include <hip/hip_runtime.h>
#include <cstdint>

#define DEVI __device__ __forceinline__

typedef __bf16 bf16x8 __attribute__((ext_vector_type(8)));
typedef float  f32x4  __attribute__((ext_vector_type(4)));

DEVI unsigned short f2b(float f){
  unsigned u = __builtin_bit_cast(unsigned, f);
  unsigned r = u + 0x7FFF + ((u >> 16) & 1);
  return (unsigned short)(r >> 16);
}
DEVI float b2f(unsigned short s){
  unsigned u = ((unsigned)s) << 16;
  return __builtin_bit_cast(float, u);
}
DEVI float gelu_f(float x){
  float u = 0.7978845608028654f * (x + 0.044715f * x * x * x);
  float e = __expf(2.0f * u);
  return x * (1.0f - 1.0f / (e + 1.0f));   // == 0.5x(1+tanh(u)), safe at e->inf / e->0
}
DEVI void gl_lds16(const unsigned short* g, unsigned short* l){
  __builtin_amdgcn_global_load_lds(
      (const __attribute__((address_space(1))) unsigned int*)g,
      (__attribute__((address_space(3))) unsigned int*)l, 16, 0, 0);
}

// ---------------- weight transpose + fp32->bf16: in[R][C] f32 -> out[C][R] bf16 ----
__global__ __launch_bounds__(256)
void transpose_f2b(const float* __restrict__ in, unsigned short* __restrict__ out,
                   int R, int C)
{
  __shared__ float tile[32][33];
  int nbx = C >> 5;
  int bx = blockIdx.x % nbx, by = blockIdx.x / nbx;
  int c0 = bx << 5, r0 = by << 5;
  int tx = threadIdx.x & 31, ty = threadIdx.x >> 5;   // 32 x 8
  #pragma unroll
  for (int j = 0; j < 32; j += 8)
    tile[ty + j][tx] = in[(size_t)(r0 + ty + j) * C + c0 + tx];
  __syncthreads();
  #pragma unroll
  for (int j = 0; j < 32; j += 8)
    out[(size_t)(c0 + ty + j) * R + r0 + tx] = f2b(tile[tx][ty + j]);
}

// ---------------- RMSNorm: x f32 [rows][768] -> out bf16, 1 wave per row ----------
__global__ __launch_bounds__(256)
void rmsnorm_k(const float* __restrict__ x, const float* __restrict__ g,
               unsigned short* __restrict__ out)
{
  int wid = threadIdx.x >> 6, lane = threadIdx.x & 63;
  size_t row = (size_t)blockIdx.x * 4 + wid;
  const float* xr = x + row * 768;
  float4 v[3];
  float ss = 0.0f;
  #pragma unroll
  for (int c = 0; c < 3; c++){
    v[c] = *(const float4*)&xr[lane * 4 + c * 256];
    ss += v[c].x * v[c].x + v[c].y * v[c].y + v[c].z * v[c].z + v[c].w * v[c].w;
  }
  #pragma unroll
  for (int o = 32; o >= 1; o >>= 1) ss += __shfl_xor(ss, o);
  float rs = rsqrtf(ss * (1.0f / 768.0f) + 1e-6f);
  #pragma unroll
  for (int c = 0; c < 3; c++){
    const float4 gv = *(const float4*)&g[lane * 4 + c * 256];
    ushort4 o4;
    o4.x = f2b(v[c].x * rs * gv.x);
    o4.y = f2b(v[c].y * rs * gv.y);
    o4.z = f2b(v[c].z * rs * gv.z);
    o4.w = f2b(v[c].w * rs * gv.w);
    *(ushort4*)&out[row * 768 + lane * 4 + c * 256] = o4;
  }
}

// ---------------- GEMM 128x192, BK=64, TRIPLE-buffer counted-vmcnt pipeline -------
// C[M,N] = A[M,K](bf16) * Bt[N,K](bf16)^T, fused epilogue.
// 4 waves 2x2, per-wave 64x96 (4 m-frags x 6 n-frags). LDS = 3 x (128+192)x64 bf16
// = 120 KB -> 1 block/CU, but NO vmcnt drain in the main loop:
//   tile t: issue stage(t+2) [10 gl_lds/wave] -> vmcnt(20) (allows t+1,t+2 in
//   flight; guarantees t landed) -> barrier -> compute -> barrier.
// Stage(t+2) overwrites buf[(t-1)%3], protected by end-of-(t-1) barrier.
// XOR swizzle as r5 (linear DMA dest, inverse-swizzled source, XOR on read).
// Requires M%128==0, N%192==0, K%64==0, grid%8==0.
template<bool BIAS, bool GELU_, bool RES, bool OUTF32>
__global__ __launch_bounds__(256, 1)
void gemm_tri(const unsigned short* __restrict__ A, const unsigned short* __restrict__ Bt,
              const float* __restrict__ bias, const float* __restrict__ res,
              void* __restrict__ outp, int M, int N, int K)
{
  constexpr int NF = 6;                       // n-frags per wave (192/32)
  constexpr int RSZ = (128 + 192) * 64;       // shorts per buffer
  __shared__ unsigned short sm[3][RSZ];

  int tid = threadIdx.x, wid = tid >> 6, lane = tid & 63;
  int la = lane & 15, hi = lane >> 4;
  int wm = wid >> 1, wn = wid & 1;
  int tiles_n = N / 192;
  int bid = blockIdx.x;
  bid = (bid & 7) * (gridDim.x >> 3) + (bid >> 3);   // XCD-aware swizzle
  int m0 = (bid / tiles_n) * 128, n0 = (bid % tiles_n) * 192;
  int NT = K >> 6;

  f32x4 acc[4][NF] = {};

  auto stage = [&](unsigned short* buf, int kt){
    #pragma unroll
    for (int l = 0; l < 4; l++){              // A: 128x64 = 1024 chunks
      int cb = wid * 256 + l * 64;
      int idx = cb + lane;
      int row = idx >> 3, sl2 = (idx & 7) ^ (row & 7);
      gl_lds16(A + (size_t)(m0 + row) * K + kt + sl2 * 8, buf + cb * 8);
    }
    #pragma unroll
    for (int l = 0; l < 6; l++){              // B: 192x64 = 1536 chunks
      int cb = wid * 384 + l * 64;
      int idx = cb + lane;
      int row = idx >> 3, sl2 = (idx & 7) ^ (row & 7);
      gl_lds16(Bt + (size_t)(n0 + row) * K + kt + sl2 * 8, buf + 8192 + cb * 8);
    }
  };

  auto compute = [&](const unsigned short* buf){
    const unsigned short* As = buf;
    const unsigned short* Bs = buf + 8192;
    #pragma unroll
    for (int kk = 0; kk < 2; kk++){
      bf16x8 afr[4], bfr[NF];
      #pragma unroll
      for (int mm = 0; mm < 4; mm++){
        int r = wm * 64 + mm * 16 + la;
        afr[mm] = *(const bf16x8*)&As[r * 64 + ((kk * 4 + hi) ^ (r & 7)) * 8];
      }
      #pragma unroll
      for (int nn = 0; nn < NF; nn++){
        int r = wn * 96 + nn * 16 + la;
        bfr[nn] = *(const bf16x8*)&Bs[r * 64 + ((kk * 4 + hi) ^ (r & 7)) * 8];
      }
      #pragma unroll
      for (int mm = 0; mm < 4; mm++)
        #pragma unroll
        for (int nn = 0; nn < NF; nn++)
          acc[mm][nn] = __builtin_amdgcn_mfma_f32_16x16x32_bf16(
              afr[mm], bfr[nn], acc[mm][nn], 0, 0, 0);
    }
  };

  // ---- prologue: stage tiles 0 and 1
  stage(sm[0], 0);
  stage(sm[1], 64);

  int cur = 0;
  for (int t = 0; t < NT; t++){
    if (t + 2 < NT)
      stage(sm[cur + 2 >= 3 ? cur - 1 : cur + 2], (t + 2) << 6);
    if (t + 2 < NT)      asm volatile("s_waitcnt vmcnt(20)" ::: "memory");
    else if (t + 1 < NT) asm volatile("s_waitcnt vmcnt(10)" ::: "memory");
    else                 asm volatile("s_waitcnt vmcnt(0)"  ::: "memory");
    __builtin_amdgcn_s_barrier();             // everyone's stage(t) visible
    compute(sm[cur]);
    __builtin_amdgcn_s_barrier();             // reads done before buf reuse
    cur = (cur == 2) ? 0 : cur + 1;
  }

  // ---- epilogue
  float* outF = (float*)outp;
  unsigned short* outB = (unsigned short*)outp;
  #pragma unroll
  for (int mm = 0; mm < 4; mm++){
    int rowb = m0 + wm * 64 + mm * 16 + hi * 4;
    #pragma unroll
    for (int nn = 0; nn < NF; nn++){
      int col = n0 + wn * 96 + nn * 16 + la;
      float bv = BIAS ? bias[col] : 0.0f;
      #pragma unroll
      for (int r = 0; r < 4; r++){
        float val = acc[mm][nn][r] + bv;
        if (GELU_) val = gelu_f(val);
        if (RES)   val += res[(size_t)(rowb + r) * N + col];
        size_t o = (size_t)(rowb + r) * N + col;
        if (OUTF32) outF[o] = val;
        else        outB[o] = f2b(val);
      }
    }
  }
}

// ---------------- sliding-window causal attention, W=64, D=64, MFMA tile ----------
__global__ __launch_bounds__(256)
void attn_k(const unsigned short* __restrict__ qkv, unsigned short* __restrict__ attn)
{
  __shared__ unsigned short Qs[64 * 72];       // stride 72: b128 reads at 8-way min
  __shared__ unsigned short Ks[128 * 72];
  __shared__ unsigned short Vt[64 * 136];      // V^T [d][s], stride 136
  __shared__ unsigned short Ps[4][16 * 136];   // per-wave P rows

  int tid = threadIdx.x, wid = tid >> 6, lane = tid & 63;
  int la = lane & 15, hi = lane >> 4;
  int blk = blockIdx.x;
  blk = (blk & 7) * (gridDim.x >> 3) + (blk >> 3);   // XCD swizzle (1536 % 8 == 0)
  int tile = blk & 15, hb = blk >> 4;
  int h = hb % 12, b = hb / 12;
  int t0 = tile << 6;

  const unsigned short* qbase = qkv + (size_t)(b * 1024) * 2304 + h * 64;

  // ---- stage Q: 64 rows x 8 chunks of 8 bf16
  #pragma unroll
  for (int r = 0; r < 2; r++){
    int idx = tid + r * 256;
    int row = idx >> 3, ch = idx & 7;
    uint4 v = *(const uint4*)(qbase + (size_t)(t0 + row) * 2304 + ch * 8);
    *(uint4*)&Qs[row * 72 + ch * 8] = v;
  }
  // ---- stage K: 128 rows (clamped at s_global<0; masked later)
  #pragma unroll
  for (int r = 0; r < 4; r++){
    int idx = tid + r * 256;
    int row = idx >> 3, ch = idx & 7;
    int sg = t0 - 64 + row; sg = sg < 0 ? 0 : sg;
    uint4 v = *(const uint4*)(qbase + 768 + (size_t)sg * 2304 + ch * 8);
    *(uint4*)&Ks[row * 72 + ch * 8] = v;
  }
  // ---- stage V transposed (s-major lane assignment -> 2-way LDS writes)
  #pragma unroll
  for (int r = 0; r < 4; r++){
    int idx = tid + r * 256;
    int s = idx & 127, ch = idx >> 7;
    int sg = t0 - 64 + s; sg = sg < 0 ? 0 : sg;
    uint4 v = *(const uint4*)(qbase + 1536 + (size_t)sg * 2304 + ch * 8);
    unsigned short tmp[8];
    *(uint4*)tmp = v;
    #pragma unroll
    for (int j = 0; j < 8; j++)
      Vt[(ch * 8 + j) * 136 + s] = tmp[j];
  }
  __syncthreads();

  // ---- S = Q K^T for 16 own rows x 128 cols (8 col-fragments x 2 k-steps)
  f32x4 sc[8];
  #pragma unroll
  for (int sj = 0; sj < 8; sj++) sc[sj] = (f32x4){0.f, 0.f, 0.f, 0.f};
  #pragma unroll
  for (int kk = 0; kk < 2; kk++){
    bf16x8 aq = *(const bf16x8*)&Qs[(wid * 16 + la) * 72 + kk * 32 + hi * 8];
    #pragma unroll
    for (int sj = 0; sj < 8; sj++){
      bf16x8 bk = *(const bf16x8*)&Ks[(sj * 16 + la) * 72 + kk * 32 + hi * 8];
      sc[sj] = __builtin_amdgcn_mfma_f32_16x16x32_bf16(aq, bk, sc[sj], 0, 0, 0);
    }
  }

  // ---- masked in-register softmax (row = wid*16 + hi*4 + r2, col = sj*16 + la)
  float inv[4];
  #pragma unroll
  for (int r2 = 0; r2 < 4; r2++){
    int row = wid * 16 + hi * 4 + r2;
    float mx = -1e30f;
    #pragma unroll
    for (int sj = 0; sj < 8; sj++){
      int sl = sj * 16 + la;
      bool valid = (sl >= row + 1) && (sl <= row + 64) && (t0 - 64 + sl >= 0);
      float sv = valid ? sc[sj][r2] * 0.125f : -1e30f;
      sc[sj][r2] = sv;
      mx = fmaxf(mx, sv);
    }
    #pragma unroll
    for (int o = 8; o >= 1; o >>= 1) mx = fmaxf(mx, __shfl_xor(mx, o));
    float sum = 0.0f;
    #pragma unroll
    for (int sj = 0; sj < 8; sj++){
      float p = __expf(sc[sj][r2] - mx);
      sc[sj][r2] = p;
      sum += p;
    }
    #pragma unroll
    for (int o = 8; o >= 1; o >>= 1) sum += __shfl_xor(sum, o);
    inv[r2] = 1.0f / sum;
  }

  // ---- P -> LDS (bf16), per-wave region
  unsigned short* myP = Ps[wid];
  #pragma unroll
  for (int sj = 0; sj < 8; sj++)
    #pragma unroll
    for (int r2 = 0; r2 < 4; r2++)
      myP[(hi * 4 + r2) * 136 + sj * 16 + la] = f2b(sc[sj][r2]);

  __syncthreads();

  // ---- O = P V  (A = P[16x128], B^T = Vt[64x128], 4 n-frags x 4 k-steps)
  f32x4 oacc[4];
  #pragma unroll
  for (int nj = 0; nj < 4; nj++) oacc[nj] = (f32x4){0.f, 0.f, 0.f, 0.f};
  #pragma unroll
  for (int ks = 0; ks < 4; ks++){
    bf16x8 ap = *(const bf16x8*)&myP[la * 136 + ks * 32 + hi * 8];
    #pragma unroll
    for (int nj = 0; nj < 4; nj++){
      bf16x8 bv = *(const bf16x8*)&Vt[(nj * 16 + la) * 136 + ks * 32 + hi * 8];
      oacc[nj] = __builtin_amdgcn_mfma_f32_16x16x32_bf16(ap, bv, oacc[nj], 0, 0, 0);
    }
  }

  // ---- write O (bf16, head-concat layout), scaled by 1/rowsum
  unsigned short* obase = attn + (size_t)(b * 1024 + t0) * 768 + h * 64;
  #pragma unroll
  for (int nj = 0; nj < 4; nj++)
    #pragma unroll
    for (int r2 = 0; r2 < 4; r2++){
      int row = wid * 16 + hi * 4 + r2;
      obase[(size_t)row * 768 + nj * 16 + la] = f2b(oacc[nj][r2] * inv[r2]);
    }
}

__global__ void aux_k(float* p){ if (threadIdx.x == 0) p[0] = 0.0f; }

// ----------------------------------------------------------------------------------
extern "C" void kernel_launch(void* const* d_in, const int* in_sizes, int n_in,
                              void* d_out, int out_size, void* d_ws, size_t ws_size,
                              hipStream_t stream)
{
  const float* x      = (const float*)d_in[0];
  const float* w_q    = (const float*)d_in[1];
  const float* w_k    = (const float*)d_in[2];
  const float* w_v    = (const float*)d_in[3];
  const float* w_proj = (const float*)d_in[4];
  const float* b_proj = (const float*)d_in[5];
  const float* w_ff1  = (const float*)d_in[6];
  const float* b_ff1  = (const float*)d_in[7];
  const float* w_ff2  = (const float*)d_in[8];
  const float* b_ff2  = (const float*)d_in[9];
  const float* g1     = (const float*)d_in[10];
  const float* g2     = (const float*)d_in[11];
  float* out = (float*)d_out;

  char* ws = (char*)d_ws;
  size_t off = 0;
  auto alloc = [&](size_t bytes){ size_t r = off; off += (bytes + 255) & ~(size_t)255; return r; };
  const size_t BT = 8 * 1024;  // 8192 rows

  unsigned short* h     = (unsigned short*)(ws + alloc(BT * 768 * 2));   // reused for attn out
  unsigned short* qkv   = (unsigned short*)(ws + alloc(BT * 3072 * 2));  // reused for ffa
  float*          x2    = (float*)         (ws + alloc(BT * 768 * 4));
  unsigned short* h2    = (unsigned short*)(ws + alloc(BT * 768 * 2));
  unsigned short* WqkvT = (unsigned short*)(ws + alloc(2304 * 768 * 2));
  unsigned short* WprojT= (unsigned short*)(ws + alloc(768 * 768 * 2));
  unsigned short* Wff1T = (unsigned short*)(ws + alloc(3072 * 768 * 2));
  unsigned short* Wff2T = (unsigned short*)(ws + alloc(768 * 3072 * 2));
  unsigned short* attn  = h;     // h dead after QKV GEMM
  unsigned short* ffa   = qkv;   // qkv dead after attention

  // weights -> bf16, transposed to [N][K]
  transpose_f2b<<<576, 256, 0, stream>>>(w_q,    WqkvT,             768, 768);
  transpose_f2b<<<576, 256, 0, stream>>>(w_k,    WqkvT + 768 * 768, 768, 768);
  transpose_f2b<<<576, 256, 0, stream>>>(w_v,    WqkvT + 1536 * 768,768, 768);
  transpose_f2b<<<576, 256, 0, stream>>>(w_proj, WprojT,            768, 768);
  transpose_f2b<<<24 * 96, 256, 0, stream>>>(w_ff1, Wff1T, 768, 3072);
  transpose_f2b<<<96 * 24, 256, 0, stream>>>(w_ff2, Wff2T, 3072, 768);

  // h = rmsnorm(x, g1)
  rmsnorm_k<<<2048, 256, 0, stream>>>(x, g1, h);

  // qkv = h @ [Wq|Wk|Wv]   (M=8192, N=2304, K=768) — grid 768 = 3 exact CU rounds
  gemm_tri<false,false,false,false><<<768, 256, 0, stream>>>(h, WqkvT, nullptr, nullptr, qkv, 8192, 2304, 768);

  // sliding-window attention -> attn (bf16, [B*T][768] head-concat layout)
  attn_k<<<8 * 12 * 16, 256, 0, stream>>>(qkv, attn);

  // x2 = x + attn @ Wproj + b_proj   (fp32 out) — grid 256 = 1 exact round
  gemm_tri<true,false,true,true><<<256, 256, 0, stream>>>(attn, WprojT, b_proj, x, x2, 8192, 768, 768);

  // h2 = rmsnorm(x2, g2)
  rmsnorm_k<<<2048, 256, 0, stream>>>(x2, g2, h2);

  // ffa = gelu(h2 @ Wff1 + b_ff1)   (M=8192, N=3072, K=768) — grid 1024 = 4 rounds
  gemm_tri<true,true,false,false><<<1024, 256, 0, stream>>>(h2, Wff1T, b_ff1, nullptr, ffa, 8192, 3072, 768);

  // out = x2 + ffa @ Wff2 + b_ff2   (M=8192, N=768, K=3072) — grid 256 = 1 round
  gemm_tri<true,false,true,true><<<256, 256, 0, stream>>>(ffa, Wff2T, b_ff2, x2, out, 8192, 768, 3072);

  // aux scalar
  aux_k<<<1, 64, 0, stream>>>(out + 6291456);
}

// Round 7
// 223.736 us; speedup vs baseline: 1.0407x; 1.0407x over previous
//
#include <hip/hip_runtime.h>
#include <cstdint>

#define DEVI __device__ __forceinline__

typedef __bf16 bf16x8 __attribute__((ext_vector_type(8)));
typedef float  f32x4  __attribute__((ext_vector_type(4)));

DEVI unsigned short f2b(float f){
  unsigned u = __builtin_bit_cast(unsigned, f);
  unsigned r = u + 0x7FFF + ((u >> 16) & 1);
  return (unsigned short)(r >> 16);
}
DEVI float b2f(unsigned short s){
  unsigned u = ((unsigned)s) << 16;
  return __builtin_bit_cast(float, u);
}
DEVI float gelu_f(float x){
  float u = 0.7978845608028654f * (x + 0.044715f * x * x * x);
  float e = __expf(2.0f * u);
  return x * (1.0f - 1.0f / (e + 1.0f));   // == 0.5x(1+tanh(u)), safe at e->inf / e->0
}
DEVI void gl_lds16(const unsigned short* g, unsigned short* l){
  __builtin_amdgcn_global_load_lds(
      (const __attribute__((address_space(1))) unsigned int*)g,
      (__attribute__((address_space(3))) unsigned int*)l, 16, 0, 0);
}

// ---------------- weight transpose + fp32->bf16: in[R][C] f32 -> out[C][R] bf16 ----
__global__ __launch_bounds__(256)
void transpose_f2b(const float* __restrict__ in, unsigned short* __restrict__ out,
                   int R, int C)
{
  __shared__ float tile[32][33];
  int nbx = C >> 5;
  int bx = blockIdx.x % nbx, by = blockIdx.x / nbx;
  int c0 = bx << 5, r0 = by << 5;
  int tx = threadIdx.x & 31, ty = threadIdx.x >> 5;   // 32 x 8
  #pragma unroll
  for (int j = 0; j < 32; j += 8)
    tile[ty + j][tx] = in[(size_t)(r0 + ty + j) * C + c0 + tx];
  __syncthreads();
  #pragma unroll
  for (int j = 0; j < 32; j += 8)
    out[(size_t)(c0 + ty + j) * R + r0 + tx] = f2b(tile[tx][ty + j]);
}

// ---------------- RMSNorm: x f32 [rows][768] -> out bf16, 1 wave per row ----------
__global__ __launch_bounds__(256)
void rmsnorm_k(const float* __restrict__ x, const float* __restrict__ g,
               unsigned short* __restrict__ out)
{
  int wid = threadIdx.x >> 6, lane = threadIdx.x & 63;
  size_t row = (size_t)blockIdx.x * 4 + wid;
  const float* xr = x + row * 768;
  float4 v[3];
  float ss = 0.0f;
  #pragma unroll
  for (int c = 0; c < 3; c++){
    v[c] = *(const float4*)&xr[lane * 4 + c * 256];
    ss += v[c].x * v[c].x + v[c].y * v[c].y + v[c].z * v[c].z + v[c].w * v[c].w;
  }
  #pragma unroll
  for (int o = 32; o >= 1; o >>= 1) ss += __shfl_xor(ss, o);
  float rs = rsqrtf(ss * (1.0f / 768.0f) + 1e-6f);
  #pragma unroll
  for (int c = 0; c < 3; c++){
    const float4 gv = *(const float4*)&g[lane * 4 + c * 256];
    ushort4 o4;
    o4.x = f2b(v[c].x * rs * gv.x);
    o4.y = f2b(v[c].y * rs * gv.y);
    o4.z = f2b(v[c].z * rs * gv.z);
    o4.w = f2b(v[c].w * rs * gv.w);
    *(ushort4*)&out[row * 768 + lane * 4 + c * 256] = o4;
  }
}

// ---------------- GEMM BMx128, BK=64, dbuf, COUNTED-vmcnt pipeline ----------------
// C[M,N] = A[M,K](bf16) * Bt[N,K](bf16)^T, fused epilogue.
// 4 waves 2x2, per-wave (BM/2)x64. LDS = 2 x (BM+128)x64 bf16:
//   BM=128 -> 64 KB (2 blocks/CU), BM=64 -> 48 KB (3 blocks/CU).
// XOR swizzle (r5, verified conflict-free): linear DMA dest, inverse-swizzled
// per-lane global source, same XOR on read.
// Pipeline (T4): tile t: issue stage(t+1) -> vmcnt(LOADS) [stage(t) landed,
// stage(t+1) stays in flight] -> barrier -> compute(t) -> barrier. Loads get a
// FULL tile of slack; no drain in the main loop (r5/r6 lesson).
// Race ledger: stage(t+1) overwrites buf[(t+1)&1]; its last readers were
// compute(t-1), fenced by the end-of-(t-1) barrier preceding this issue.
// Requires M%BM==0, N%128==0, K%64==0, grid%8==0.
template<int BM, bool BIAS, bool GELU_, bool RES, bool OUTF32>
__global__ __launch_bounds__(256, BM == 64 ? 3 : 2)
void gemm_db(const unsigned short* __restrict__ A, const unsigned short* __restrict__ Bt,
             const float* __restrict__ bias, const float* __restrict__ res,
             void* __restrict__ outp, int M, int N, int K)
{
  constexpr int MI = BM / 32;             // m-frags per wave
  constexpr int AL = (BM * 8) / 256;      // A-stage instrs per wave
  __shared__ unsigned short sm[2][(BM + 128) * 64];

  int tid = threadIdx.x, wid = tid >> 6, lane = tid & 63;
  int la = lane & 15, hi = lane >> 4;
  int wm = wid >> 1, wn = wid & 1;        // 2x2 waves
  int tiles_n = N >> 7;
  int bid = blockIdx.x;
  bid = (bid & 7) * (gridDim.x >> 3) + (bid >> 3);   // XCD-aware swizzle
  int m0 = (bid / tiles_n) * BM, n0 = (bid % tiles_n) << 7;
  int NT = K >> 6;

  f32x4 acc[MI][4] = {};

  auto stage = [&](unsigned short* buf, int kt){
    #pragma unroll
    for (int l = 0; l < AL; l++){
      int cb  = wid * (BM * 2) + l * 64;          // wave-uniform chunk base
      int idx = cb + lane;
      int row = idx >> 3, slot = idx & 7, sl2 = slot ^ (row & 7);
      gl_lds16(A + (size_t)(m0 + row) * K + kt + sl2 * 8, buf + cb * 8);
    }
    #pragma unroll
    for (int l = 0; l < 4; l++){
      int cb  = wid * 256 + l * 64;
      int idx = cb + lane;
      int row = idx >> 3, slot = idx & 7, sl2 = slot ^ (row & 7);
      gl_lds16(Bt + (size_t)(n0 + row) * K + kt + sl2 * 8, buf + BM * 64 + cb * 8);
    }
  };

  stage(sm[0], 0);

  for (int t = 0; t < NT; t++){
    const unsigned short* As = sm[t & 1];
    const unsigned short* Bs = sm[t & 1] + BM * 64;

    if (t + 1 < NT){
      stage(sm[(t + 1) & 1], (t + 1) << 6);
      // stage(t)'s loads are the oldest; allow stage(t+1)'s (AL+4) to stay in flight
      if constexpr (BM == 128) asm volatile("s_waitcnt vmcnt(8)" ::: "memory");
      else                     asm volatile("s_waitcnt vmcnt(6)" ::: "memory");
    } else {
      asm volatile("s_waitcnt vmcnt(0)" ::: "memory");
    }
    __builtin_amdgcn_s_barrier();                      // buf[t&1] visible to all

    bf16x8 afr[MI][2], bfr[4][2];
    #pragma unroll
    for (int mm = 0; mm < MI; mm++)
      #pragma unroll
      for (int kk = 0; kk < 2; kk++){
        int r = wm * (BM / 2) + mm * 16 + la;
        afr[mm][kk] = *(const bf16x8*)&As[r * 64 + (((kk * 4 + hi) ^ (r & 7))) * 8];
      }
    #pragma unroll
    for (int nn = 0; nn < 4; nn++)
      #pragma unroll
      for (int kk = 0; kk < 2; kk++){
        int r = wn * 64 + nn * 16 + la;
        bfr[nn][kk] = *(const bf16x8*)&Bs[r * 64 + (((kk * 4 + hi) ^ (r & 7))) * 8];
      }
    __builtin_amdgcn_s_setprio(1);
    #pragma unroll
    for (int mm = 0; mm < MI; mm++)
      #pragma unroll
      for (int nn = 0; nn < 4; nn++)
        #pragma unroll
        for (int kk = 0; kk < 2; kk++)
          acc[mm][nn] = __builtin_amdgcn_mfma_f32_16x16x32_bf16(
              afr[mm][kk], bfr[nn][kk], acc[mm][nn], 0, 0, 0);
    __builtin_amdgcn_s_setprio(0);

    __builtin_amdgcn_s_barrier();                      // reads done before buf reuse
  }

  float* outF = (float*)outp;
  unsigned short* outB = (unsigned short*)outp;
  #pragma unroll
  for (int mm = 0; mm < MI; mm++){
    int rowb = m0 + wm * (BM / 2) + mm * 16 + hi * 4;
    #pragma unroll
    for (int nn = 0; nn < 4; nn++){
      int col = n0 + wn * 64 + nn * 16 + la;
      float bv = BIAS ? bias[col] : 0.0f;
      #pragma unroll
      for (int r = 0; r < 4; r++){
        float val = acc[mm][nn][r] + bv;
        if (GELU_) val = gelu_f(val);
        if (RES)   val += res[(size_t)(rowb + r) * N + col];
        size_t o = (size_t)(rowb + r) * N + col;
        if (OUTF32) outF[o] = val;
        else        outB[o] = f2b(val);
      }
    }
  }
}

// ---------------- sliding-window causal attention, W=64, D=64, MFMA tile ----------
__global__ __launch_bounds__(256)
void attn_k(const unsigned short* __restrict__ qkv, unsigned short* __restrict__ attn)
{
  __shared__ unsigned short Qs[64 * 72];       // stride 72: b128 reads at 8-way min
  __shared__ unsigned short Ks[128 * 72];
  __shared__ unsigned short Vt[64 * 136];      // V^T [d][s], stride 136
  __shared__ unsigned short Ps[4][16 * 136];   // per-wave P rows

  int tid = threadIdx.x, wid = tid >> 6, lane = tid & 63;
  int la = lane & 15, hi = lane >> 4;
  int blk = blockIdx.x;
  blk = (blk & 7) * (gridDim.x >> 3) + (blk >> 3);   // XCD swizzle (1536 % 8 == 0)
  int tile = blk & 15, hb = blk >> 4;
  int h = hb % 12, b = hb / 12;
  int t0 = tile << 6;

  const unsigned short* qbase = qkv + (size_t)(b * 1024) * 2304 + h * 64;

  // ---- stage Q: 64 rows x 8 chunks of 8 bf16
  #pragma unroll
  for (int r = 0; r < 2; r++){
    int idx = tid + r * 256;
    int row = idx >> 3, ch = idx & 7;
    uint4 v = *(const uint4*)(qbase + (size_t)(t0 + row) * 2304 + ch * 8);
    *(uint4*)&Qs[row * 72 + ch * 8] = v;
  }
  // ---- stage K: 128 rows (clamped at s_global<0; masked later)
  #pragma unroll
  for (int r = 0; r < 4; r++){
    int idx = tid + r * 256;
    int row = idx >> 3, ch = idx & 7;
    int sg = t0 - 64 + row; sg = sg < 0 ? 0 : sg;
    uint4 v = *(const uint4*)(qbase + 768 + (size_t)sg * 2304 + ch * 8);
    *(uint4*)&Ks[row * 72 + ch * 8] = v;
  }
  // ---- stage V transposed (s-major lane assignment -> 2-way LDS writes)
  #pragma unroll
  for (int r = 0; r < 4; r++){
    int idx = tid + r * 256;
    int s = idx & 127, ch = idx >> 7;
    int sg = t0 - 64 + s; sg = sg < 0 ? 0 : sg;
    uint4 v = *(const uint4*)(qbase + 1536 + (size_t)sg * 2304 + ch * 8);
    unsigned short tmp[8];
    *(uint4*)tmp = v;
    #pragma unroll
    for (int j = 0; j < 8; j++)
      Vt[(ch * 8 + j) * 136 + s] = tmp[j];
  }
  __syncthreads();

  // ---- S = Q K^T for 16 own rows x 128 cols (8 col-fragments x 2 k-steps)
  f32x4 sc[8];
  #pragma unroll
  for (int sj = 0; sj < 8; sj++) sc[sj] = (f32x4){0.f, 0.f, 0.f, 0.f};
  #pragma unroll
  for (int kk = 0; kk < 2; kk++){
    bf16x8 aq = *(const bf16x8*)&Qs[(wid * 16 + la) * 72 + kk * 32 + hi * 8];
    #pragma unroll
    for (int sj = 0; sj < 8; sj++){
      bf16x8 bk = *(const bf16x8*)&Ks[(sj * 16 + la) * 72 + kk * 32 + hi * 8];
      sc[sj] = __builtin_amdgcn_mfma_f32_16x16x32_bf16(aq, bk, sc[sj], 0, 0, 0);
    }
  }

  // ---- masked in-register softmax (row = wid*16 + hi*4 + r2, col = sj*16 + la)
  float inv[4];
  #pragma unroll
  for (int r2 = 0; r2 < 4; r2++){
    int row = wid * 16 + hi * 4 + r2;
    float mx = -1e30f;
    #pragma unroll
    for (int sj = 0; sj < 8; sj++){
      int sl = sj * 16 + la;
      bool valid = (sl >= row + 1) && (sl <= row + 64) && (t0 - 64 + sl >= 0);
      float sv = valid ? sc[sj][r2] * 0.125f : -1e30f;
      sc[sj][r2] = sv;
      mx = fmaxf(mx, sv);
    }
    #pragma unroll
    for (int o = 8; o >= 1; o >>= 1) mx = fmaxf(mx, __shfl_xor(mx, o));
    float sum = 0.0f;
    #pragma unroll
    for (int sj = 0; sj < 8; sj++){
      float p = __expf(sc[sj][r2] - mx);
      sc[sj][r2] = p;
      sum += p;
    }
    #pragma unroll
    for (int o = 8; o >= 1; o >>= 1) sum += __shfl_xor(sum, o);
    inv[r2] = 1.0f / sum;
  }

  // ---- P -> LDS (bf16), per-wave region
  unsigned short* myP = Ps[wid];
  #pragma unroll
  for (int sj = 0; sj < 8; sj++)
    #pragma unroll
    for (int r2 = 0; r2 < 4; r2++)
      myP[(hi * 4 + r2) * 136 + sj * 16 + la] = f2b(sc[sj][r2]);

  __syncthreads();

  // ---- O = P V  (A = P[16x128], B^T = Vt[64x128], 4 n-frags x 4 k-steps)
  f32x4 oacc[4];
  #pragma unroll
  for (int nj = 0; nj < 4; nj++) oacc[nj] = (f32x4){0.f, 0.f, 0.f, 0.f};
  #pragma unroll
  for (int ks = 0; ks < 4; ks++){
    bf16x8 ap = *(const bf16x8*)&myP[la * 136 + ks * 32 + hi * 8];
    #pragma unroll
    for (int nj = 0; nj < 4; nj++){
      bf16x8 bv = *(const bf16x8*)&Vt[(nj * 16 + la) * 136 + ks * 32 + hi * 8];
      oacc[nj] = __builtin_amdgcn_mfma_f32_16x16x32_bf16(ap, bv, oacc[nj], 0, 0, 0);
    }
  }

  // ---- write O (bf16, head-concat layout), scaled by 1/rowsum
  unsigned short* obase = attn + (size_t)(b * 1024 + t0) * 768 + h * 64;
  #pragma unroll
  for (int nj = 0; nj < 4; nj++)
    #pragma unroll
    for (int r2 = 0; r2 < 4; r2++){
      int row = wid * 16 + hi * 4 + r2;
      obase[(size_t)row * 768 + nj * 16 + la] = f2b(oacc[nj][r2] * inv[r2]);
    }
}

__global__ void aux_k(float* p){ if (threadIdx.x == 0) p[0] = 0.0f; }

// ----------------------------------------------------------------------------------
extern "C" void kernel_launch(void* const* d_in, const int* in_sizes, int n_in,
                              void* d_out, int out_size, void* d_ws, size_t ws_size,
                              hipStream_t stream)
{
  const float* x      = (const float*)d_in[0];
  const float* w_q    = (const float*)d_in[1];
  const float* w_k    = (const float*)d_in[2];
  const float* w_v    = (const float*)d_in[3];
  const float* w_proj = (const float*)d_in[4];
  const float* b_proj = (const float*)d_in[5];
  const float* w_ff1  = (const float*)d_in[6];
  const float* b_ff1  = (const float*)d_in[7];
  const float* w_ff2  = (const float*)d_in[8];
  const float* b_ff2  = (const float*)d_in[9];
  const float* g1     = (const float*)d_in[10];
  const float* g2     = (const float*)d_in[11];
  float* out = (float*)d_out;

  char* ws = (char*)d_ws;
  size_t off = 0;
  auto alloc = [&](size_t bytes){ size_t r = off; off += (bytes + 255) & ~(size_t)255; return r; };
  const size_t BT = 8 * 1024;  // 8192 rows

  unsigned short* h     = (unsigned short*)(ws + alloc(BT * 768 * 2));   // reused for attn out
  unsigned short* qkv   = (unsigned short*)(ws + alloc(BT * 3072 * 2));  // reused for ffa
  float*          x2    = (float*)         (ws + alloc(BT * 768 * 4));
  unsigned short* h2    = (unsigned short*)(ws + alloc(BT * 768 * 2));
  unsigned short* WqkvT = (unsigned short*)(ws + alloc(2304 * 768 * 2));
  unsigned short* WprojT= (unsigned short*)(ws + alloc(768 * 768 * 2));
  unsigned short* Wff1T = (unsigned short*)(ws + alloc(3072 * 768 * 2));
  unsigned short* Wff2T = (unsigned short*)(ws + alloc(768 * 3072 * 2));
  unsigned short* attn  = h;     // h dead after QKV GEMM
  unsigned short* ffa   = qkv;   // qkv dead after attention

  // weights -> bf16, transposed to [N][K]
  transpose_f2b<<<576, 256, 0, stream>>>(w_q,    WqkvT,             768, 768);
  transpose_f2b<<<576, 256, 0, stream>>>(w_k,    WqkvT + 768 * 768, 768, 768);
  transpose_f2b<<<576, 256, 0, stream>>>(w_v,    WqkvT + 1536 * 768,768, 768);
  transpose_f2b<<<576, 256, 0, stream>>>(w_proj, WprojT,            768, 768);
  transpose_f2b<<<24 * 96, 256, 0, stream>>>(w_ff1, Wff1T, 768, 3072);
  transpose_f2b<<<96 * 24, 256, 0, stream>>>(w_ff2, Wff2T, 3072, 768);

  // h = rmsnorm(x, g1)
  rmsnorm_k<<<2048, 256, 0, stream>>>(x, g1, h);

  // qkv = h @ [Wq|Wk|Wv]   (M=8192, N=2304, K=768), bf16 out
  gemm_db<128,false,false,false,false><<<64 * 18, 256, 0, stream>>>(h, WqkvT, nullptr, nullptr, qkv, 8192, 2304, 768);

  // sliding-window attention -> attn (bf16, [B*T][768] head-concat layout)
  attn_k<<<8 * 12 * 16, 256, 0, stream>>>(qkv, attn);

  // x2 = x + attn @ Wproj + b_proj   (fp32 out), BM=64 -> grid 768 (3 blocks/CU)
  gemm_db<64,true,false,true,true><<<128 * 6, 256, 0, stream>>>(attn, WprojT, b_proj, x, x2, 8192, 768, 768);

  // h2 = rmsnorm(x2, g2)
  rmsnorm_k<<<2048, 256, 0, stream>>>(x2, g2, h2);

  // ffa = gelu(h2 @ Wff1 + b_ff1)   (bf16 out, M=8192, N=3072, K=768)
  gemm_db<128,true,true,false,false><<<64 * 24, 256, 0, stream>>>(h2, Wff1T, b_ff1, nullptr, ffa, 8192, 3072, 768);

  // out = x2 + ffa @ Wff2 + b_ff2   (fp32, M=8192, N=768, K=3072), BM=64
  gemm_db<64,true,false,true,true><<<128 * 6, 256, 0, stream>>>(ffa, Wff2T, b_ff2, x2, out, 8192, 768, 3072);

  // aux scalar
  aux_k<<<1, 64, 0, stream>>>(out + 6291456);
}

// Round 8
// 220.715 us; speedup vs baseline: 1.0550x; 1.0137x over previous
//
#include <hip/hip_runtime.h>
#include <cstdint>

#define DEVI __device__ __forceinline__

typedef __bf16 bf16x8 __attribute__((ext_vector_type(8)));
typedef float  f32x4  __attribute__((ext_vector_type(4)));

template<int V> struct IC { static constexpr int v = V; };

DEVI unsigned short f2b(float f){
  unsigned u = __builtin_bit_cast(unsigned, f);
  unsigned r = u + 0x7FFF + ((u >> 16) & 1);
  return (unsigned short)(r >> 16);
}
DEVI float b2f(unsigned short s){
  unsigned u = ((unsigned)s) << 16;
  return __builtin_bit_cast(float, u);
}
DEVI float gelu_f(float x){
  float u = 0.7978845608028654f * (x + 0.044715f * x * x * x);
  float e = __expf(2.0f * u);
  return x * (1.0f - 1.0f / (e + 1.0f));   // == 0.5x(1+tanh(u)), safe at e->inf / e->0
}
DEVI void gl_lds16(const unsigned short* g, unsigned short* l){
  __builtin_amdgcn_global_load_lds(
      (const __attribute__((address_space(1))) unsigned int*)g,
      (__attribute__((address_space(3))) unsigned int*)l, 16, 0, 0);
}

// ---------------- weight transpose + fp32->bf16: in[R][C] f32 -> out[C][R] bf16 ----
__global__ __launch_bounds__(256)
void transpose_f2b(const float* __restrict__ in, unsigned short* __restrict__ out,
                   int R, int C)
{
  __shared__ float tile[32][33];
  int nbx = C >> 5;
  int bx = blockIdx.x % nbx, by = blockIdx.x / nbx;
  int c0 = bx << 5, r0 = by << 5;
  int tx = threadIdx.x & 31, ty = threadIdx.x >> 5;   // 32 x 8
  #pragma unroll
  for (int j = 0; j < 32; j += 8)
    tile[ty + j][tx] = in[(size_t)(r0 + ty + j) * C + c0 + tx];
  __syncthreads();
  #pragma unroll
  for (int j = 0; j < 32; j += 8)
    out[(size_t)(c0 + ty + j) * R + r0 + tx] = f2b(tile[tx][ty + j]);
}

// ---------------- RMSNorm: x f32 [rows][768] -> out bf16, 1 wave per row ----------
__global__ __launch_bounds__(256)
void rmsnorm_k(const float* __restrict__ x, const float* __restrict__ g,
               unsigned short* __restrict__ out)
{
  int wid = threadIdx.x >> 6, lane = threadIdx.x & 63;
  size_t row = (size_t)blockIdx.x * 4 + wid;
  const float* xr = x + row * 768;
  float4 v[3];
  float ss = 0.0f;
  #pragma unroll
  for (int c = 0; c < 3; c++){
    v[c] = *(const float4*)&xr[lane * 4 + c * 256];
    ss += v[c].x * v[c].x + v[c].y * v[c].y + v[c].z * v[c].z + v[c].w * v[c].w;
  }
  #pragma unroll
  for (int o = 32; o >= 1; o >>= 1) ss += __shfl_xor(ss, o);
  float rs = rsqrtf(ss * (1.0f / 768.0f) + 1e-6f);
  #pragma unroll
  for (int c = 0; c < 3; c++){
    const float4 gv = *(const float4*)&g[lane * 4 + c * 256];
    ushort4 o4;
    o4.x = f2b(v[c].x * rs * gv.x);
    o4.y = f2b(v[c].y * rs * gv.y);
    o4.z = f2b(v[c].z * rs * gv.z);
    o4.w = f2b(v[c].w * rs * gv.w);
    *(ushort4*)&out[row * 768 + lane * 4 + c * 256] = o4;
  }
}

// ---------------- GEMM BMx128, BK=64, dbuf, counted vmcnt, HOISTED addressing -----
// Identical schedule/numerics to r7; all addressing precomputed outside the loop:
//  - per-lane global src pointers advanced += 64/tile,
//  - per-buffer LDS DMA dest pointers,
//  - 8 fragment base pointers (swizzle is lane-constant: r&7 == la&7),
//  - tiles unrolled x2 so buffer index is compile-time (no runtime-indexed arrays).
// Requires M%BM==0, N%128==0, K%128==0, grid%8==0.
template<int BM, bool BIAS, bool GELU_, bool RES, bool OUTF32>
__global__ __launch_bounds__(256, BM == 64 ? 3 : 2)
void gemm_db(const unsigned short* __restrict__ A, const unsigned short* __restrict__ Bt,
             const float* __restrict__ bias, const float* __restrict__ res,
             void* __restrict__ outp, int M, int N, int K)
{
  constexpr int MI = BM / 32;             // m-frags per wave
  constexpr int AL = (BM * 8) / 256;      // A-stage instrs per wave
  constexpr int BUFSZ = (BM + 128) * 64;  // shorts per buffer
  __shared__ unsigned short sm[2][BUFSZ];

  int tid = threadIdx.x, wid = tid >> 6, lane = tid & 63;
  int la = lane & 15, hi = lane >> 4;
  int wm = wid >> 1, wn = wid & 1;        // 2x2 waves
  int tiles_n = N >> 7;
  int bid = blockIdx.x;
  bid = (bid & 7) * (gridDim.x >> 3) + (bid >> 3);   // XCD-aware swizzle
  int m0 = (bid / tiles_n) * BM, n0 = (bid % tiles_n) << 7;
  int NT = K >> 6;

  f32x4 acc[MI][4] = {};

  // ---- hoisted stage addressing (per-lane src, per-buffer uniform dest)
  const unsigned short* aSrc[AL];
  const unsigned short* bSrc[4];
  unsigned short* aDst[2][AL];
  unsigned short* bDst[2][4];
  #pragma unroll
  for (int l = 0; l < AL; l++){
    int cb = wid * (BM * 2) + l * 64;
    int idx = cb + lane;
    int row = idx >> 3, sl2 = (idx & 7) ^ (row & 7);
    aSrc[l] = A + (size_t)(m0 + row) * K + sl2 * 8;
    aDst[0][l] = &sm[0][cb * 8];
    aDst[1][l] = &sm[1][cb * 8];
  }
  #pragma unroll
  for (int l = 0; l < 4; l++){
    int cb = wid * 256 + l * 64;
    int idx = cb + lane;
    int row = idx >> 3, sl2 = (idx & 7) ^ (row & 7);
    bSrc[l] = Bt + (size_t)(n0 + row) * K + sl2 * 8;
    bDst[0][l] = &sm[0][BM * 64 + cb * 8];
    bDst[1][l] = &sm[1][BM * 64 + cb * 8];
  }

  // ---- hoisted fragment base pointers [buf][kk]; frag (mm|nn) at +1024 shorts each
  // (swizzle lane-constant: row&7 == la&7 since all row terms are multiples of 8)
  const unsigned short* fa[2][2];
  const unsigned short* fb[2][2];
  #pragma unroll
  for (int bf = 0; bf < 2; bf++)
    #pragma unroll
    for (int kk = 0; kk < 2; kk++){
      int sw = (((kk * 4 + hi) ^ (la & 7))) * 8;
      fa[bf][kk] = &sm[bf][(wm * (BM / 2) + la) * 64 + sw];
      fb[bf][kk] = &sm[bf][BM * 64 + (wn * 64 + la) * 64 + sw];
    }

  auto stageTo = [&](auto BF){
    constexpr int bf = decltype(BF)::v;
    #pragma unroll
    for (int l = 0; l < AL; l++){ gl_lds16(aSrc[l], aDst[bf][l]); aSrc[l] += 64; }
    #pragma unroll
    for (int l = 0; l < 4; l++){ gl_lds16(bSrc[l], bDst[bf][l]); bSrc[l] += 64; }
  };

  stageTo(IC<0>{});

  auto tile_step = [&](auto BUF, int t){
    constexpr int CB = decltype(BUF)::v;
    if (t + 1 < NT){
      stageTo(IC<CB ^ 1>{});
      // stage(t)'s loads are the oldest; allow stage(t+1)'s (AL+4) to stay in flight
      if constexpr (BM == 128) asm volatile("s_waitcnt vmcnt(8)" ::: "memory");
      else                     asm volatile("s_waitcnt vmcnt(6)" ::: "memory");
    } else {
      asm volatile("s_waitcnt vmcnt(0)" ::: "memory");
    }
    __builtin_amdgcn_s_barrier();                      // buf[CB] visible to all

    bf16x8 afr[MI][2], bfr[4][2];
    #pragma unroll
    for (int mm = 0; mm < MI; mm++){
      afr[mm][0] = *(const bf16x8*)(fa[CB][0] + mm * 1024);
      afr[mm][1] = *(const bf16x8*)(fa[CB][1] + mm * 1024);
    }
    #pragma unroll
    for (int nn = 0; nn < 4; nn++){
      bfr[nn][0] = *(const bf16x8*)(fb[CB][0] + nn * 1024);
      bfr[nn][1] = *(const bf16x8*)(fb[CB][1] + nn * 1024);
    }
    __builtin_amdgcn_s_setprio(1);
    #pragma unroll
    for (int mm = 0; mm < MI; mm++)
      #pragma unroll
      for (int nn = 0; nn < 4; nn++)
        #pragma unroll
        for (int kk = 0; kk < 2; kk++)
          acc[mm][nn] = __builtin_amdgcn_mfma_f32_16x16x32_bf16(
              afr[mm][kk], bfr[nn][kk], acc[mm][nn], 0, 0, 0);
    __builtin_amdgcn_s_setprio(0);

    __builtin_amdgcn_s_barrier();                      // reads done before buf reuse
  };

  for (int t = 0; t < NT; t += 2){                     // NT even (K%128==0)
    tile_step(IC<0>{}, t);
    tile_step(IC<1>{}, t + 1);
  }

  float* outF = (float*)outp;
  unsigned short* outB = (unsigned short*)outp;
  #pragma unroll
  for (int mm = 0; mm < MI; mm++){
    int rowb = m0 + wm * (BM / 2) + mm * 16 + hi * 4;
    #pragma unroll
    for (int nn = 0; nn < 4; nn++){
      int col = n0 + wn * 64 + nn * 16 + la;
      float bv = BIAS ? bias[col] : 0.0f;
      #pragma unroll
      for (int r = 0; r < 4; r++){
        float val = acc[mm][nn][r] + bv;
        if (GELU_) val = gelu_f(val);
        if (RES)   val += res[(size_t)(rowb + r) * N + col];
        size_t o = (size_t)(rowb + r) * N + col;
        if (OUTF32) outF[o] = val;
        else        outB[o] = f2b(val);
      }
    }
  }
}

// ---------------- sliding-window causal attention, W=64, D=64, MFMA tile ----------
__global__ __launch_bounds__(256)
void attn_k(const unsigned short* __restrict__ qkv, unsigned short* __restrict__ attn)
{
  __shared__ unsigned short Qs[64 * 72];       // stride 72: b128 reads at 8-way min
  __shared__ unsigned short Ks[128 * 72];
  __shared__ unsigned short Vt[64 * 136];      // V^T [d][s], stride 136
  __shared__ unsigned short Ps[4][16 * 136];   // per-wave P rows

  int tid = threadIdx.x, wid = tid >> 6, lane = tid & 63;
  int la = lane & 15, hi = lane >> 4;
  int blk = blockIdx.x;
  blk = (blk & 7) * (gridDim.x >> 3) + (blk >> 3);   // XCD swizzle (1536 % 8 == 0)
  int tile = blk & 15, hb = blk >> 4;
  int h = hb % 12, b = hb / 12;
  int t0 = tile << 6;

  const unsigned short* qbase = qkv + (size_t)(b * 1024) * 2304 + h * 64;

  // ---- stage Q: 64 rows x 8 chunks of 8 bf16
  #pragma unroll
  for (int r = 0; r < 2; r++){
    int idx = tid + r * 256;
    int row = idx >> 3, ch = idx & 7;
    uint4 v = *(const uint4*)(qbase + (size_t)(t0 + row) * 2304 + ch * 8);
    *(uint4*)&Qs[row * 72 + ch * 8] = v;
  }
  // ---- stage K: 128 rows (clamped at s_global<0; masked later)
  #pragma unroll
  for (int r = 0; r < 4; r++){
    int idx = tid + r * 256;
    int row = idx >> 3, ch = idx & 7;
    int sg = t0 - 64 + row; sg = sg < 0 ? 0 : sg;
    uint4 v = *(const uint4*)(qbase + 768 + (size_t)sg * 2304 + ch * 8);
    *(uint4*)&Ks[row * 72 + ch * 8] = v;
  }
  // ---- stage V transposed (s-major lane assignment -> 2-way LDS writes)
  #pragma unroll
  for (int r = 0; r < 4; r++){
    int idx = tid + r * 256;
    int s = idx & 127, ch = idx >> 7;
    int sg = t0 - 64 + s; sg = sg < 0 ? 0 : sg;
    uint4 v = *(const uint4*)(qbase + 1536 + (size_t)sg * 2304 + ch * 8);
    unsigned short tmp[8];
    *(uint4*)tmp = v;
    #pragma unroll
    for (int j = 0; j < 8; j++)
      Vt[(ch * 8 + j) * 136 + s] = tmp[j];
  }
  __syncthreads();

  // ---- S = Q K^T for 16 own rows x 128 cols (8 col-fragments x 2 k-steps)
  f32x4 sc[8];
  #pragma unroll
  for (int sj = 0; sj < 8; sj++) sc[sj] = (f32x4){0.f, 0.f, 0.f, 0.f};
  #pragma unroll
  for (int kk = 0; kk < 2; kk++){
    bf16x8 aq = *(const bf16x8*)&Qs[(wid * 16 + la) * 72 + kk * 32 + hi * 8];
    #pragma unroll
    for (int sj = 0; sj < 8; sj++){
      bf16x8 bk = *(const bf16x8*)&Ks[(sj * 16 + la) * 72 + kk * 32 + hi * 8];
      sc[sj] = __builtin_amdgcn_mfma_f32_16x16x32_bf16(aq, bk, sc[sj], 0, 0, 0);
    }
  }

  // ---- masked in-register softmax (row = wid*16 + hi*4 + r2, col = sj*16 + la)
  float inv[4];
  #pragma unroll
  for (int r2 = 0; r2 < 4; r2++){
    int row = wid * 16 + hi * 4 + r2;
    float mx = -1e30f;
    #pragma unroll
    for (int sj = 0; sj < 8; sj++){
      int sl = sj * 16 + la;
      bool valid = (sl >= row + 1) && (sl <= row + 64) && (t0 - 64 + sl >= 0);
      float sv = valid ? sc[sj][r2] * 0.125f : -1e30f;
      sc[sj][r2] = sv;
      mx = fmaxf(mx, sv);
    }
    #pragma unroll
    for (int o = 8; o >= 1; o >>= 1) mx = fmaxf(mx, __shfl_xor(mx, o));
    float sum = 0.0f;
    #pragma unroll
    for (int sj = 0; sj < 8; sj++){
      float p = __expf(sc[sj][r2] - mx);
      sc[sj][r2] = p;
      sum += p;
    }
    #pragma unroll
    for (int o = 8; o >= 1; o >>= 1) sum += __shfl_xor(sum, o);
    inv[r2] = 1.0f / sum;
  }

  // ---- P -> LDS (bf16), per-wave region
  unsigned short* myP = Ps[wid];
  #pragma unroll
  for (int sj = 0; sj < 8; sj++)
    #pragma unroll
    for (int r2 = 0; r2 < 4; r2++)
      myP[(hi * 4 + r2) * 136 + sj * 16 + la] = f2b(sc[sj][r2]);

  __syncthreads();

  // ---- O = P V  (A = P[16x128], B^T = Vt[64x128], 4 n-frags x 4 k-steps)
  f32x4 oacc[4];
  #pragma unroll
  for (int nj = 0; nj < 4; nj++) oacc[nj] = (f32x4){0.f, 0.f, 0.f, 0.f};
  #pragma unroll
  for (int ks = 0; ks < 4; ks++){
    bf16x8 ap = *(const bf16x8*)&myP[la * 136 + ks * 32 + hi * 8];
    #pragma unroll
    for (int nj = 0; nj < 4; nj++){
      bf16x8 bv = *(const bf16x8*)&Vt[(nj * 16 + la) * 136 + ks * 32 + hi * 8];
      oacc[nj] = __builtin_amdgcn_mfma_f32_16x16x32_bf16(ap, bv, oacc[nj], 0, 0, 0);
    }
  }

  // ---- write O (bf16, head-concat layout), scaled by 1/rowsum
  unsigned short* obase = attn + (size_t)(b * 1024 + t0) * 768 + h * 64;
  #pragma unroll
  for (int nj = 0; nj < 4; nj++)
    #pragma unroll
    for (int r2 = 0; r2 < 4; r2++){
      int row = wid * 16 + hi * 4 + r2;
      obase[(size_t)row * 768 + nj * 16 + la] = f2b(oacc[nj][r2] * inv[r2]);
    }
}

__global__ void aux_k(float* p){ if (threadIdx.x == 0) p[0] = 0.0f; }

// ----------------------------------------------------------------------------------
extern "C" void kernel_launch(void* const* d_in, const int* in_sizes, int n_in,
                              void* d_out, int out_size, void* d_ws, size_t ws_size,
                              hipStream_t stream)
{
  const float* x      = (const float*)d_in[0];
  const float* w_q    = (const float*)d_in[1];
  const float* w_k    = (const float*)d_in[2];
  const float* w_v    = (const float*)d_in[3];
  const float* w_proj = (const float*)d_in[4];
  const float* b_proj = (const float*)d_in[5];
  const float* w_ff1  = (const float*)d_in[6];
  const float* b_ff1  = (const float*)d_in[7];
  const float* w_ff2  = (const float*)d_in[8];
  const float* b_ff2  = (const float*)d_in[9];
  const float* g1     = (const float*)d_in[10];
  const float* g2     = (const float*)d_in[11];
  float* out = (float*)d_out;

  char* ws = (char*)d_ws;
  size_t off = 0;
  auto alloc = [&](size_t bytes){ size_t r = off; off += (bytes + 255) & ~(size_t)255; return r; };
  const size_t BT = 8 * 1024;  // 8192 rows

  unsigned short* h     = (unsigned short*)(ws + alloc(BT * 768 * 2));   // reused for attn out
  unsigned short* qkv   = (unsigned short*)(ws + alloc(BT * 3072 * 2));  // reused for ffa
  float*          x2    = (float*)         (ws + alloc(BT * 768 * 4));
  unsigned short* h2    = (unsigned short*)(ws + alloc(BT * 768 * 2));
  unsigned short* WqkvT = (unsigned short*)(ws + alloc(2304 * 768 * 2));
  unsigned short* WprojT= (unsigned short*)(ws + alloc(768 * 768 * 2));
  unsigned short* Wff1T = (unsigned short*)(ws + alloc(3072 * 768 * 2));
  unsigned short* Wff2T = (unsigned short*)(ws + alloc(768 * 3072 * 2));
  unsigned short* attn  = h;     // h dead after QKV GEMM
  unsigned short* ffa   = qkv;   // qkv dead after attention

  // weights -> bf16, transposed to [N][K]
  transpose_f2b<<<576, 256, 0, stream>>>(w_q,    WqkvT,             768, 768);
  transpose_f2b<<<576, 256, 0, stream>>>(w_k,    WqkvT + 768 * 768, 768, 768);
  transpose_f2b<<<576, 256, 0, stream>>>(w_v,    WqkvT + 1536 * 768,768, 768);
  transpose_f2b<<<576, 256, 0, stream>>>(w_proj, WprojT,            768, 768);
  transpose_f2b<<<24 * 96, 256, 0, stream>>>(w_ff1, Wff1T, 768, 3072);
  transpose_f2b<<<96 * 24, 256, 0, stream>>>(w_ff2, Wff2T, 3072, 768);

  // h = rmsnorm(x, g1)
  rmsnorm_k<<<2048, 256, 0, stream>>>(x, g1, h);

  // qkv = h @ [Wq|Wk|Wv]   (M=8192, N=2304, K=768), bf16 out
  gemm_db<128,false,false,false,false><<<64 * 18, 256, 0, stream>>>(h, WqkvT, nullptr, nullptr, qkv, 8192, 2304, 768);

  // sliding-window attention -> attn (bf16, [B*T][768] head-concat layout)
  attn_k<<<8 * 12 * 16, 256, 0, stream>>>(qkv, attn);

  // x2 = x + attn @ Wproj + b_proj   (fp32 out), BM=64 -> grid 768 (3 blocks/CU)
  gemm_db<64,true,false,true,true><<<128 * 6, 256, 0, stream>>>(attn, WprojT, b_proj, x, x2, 8192, 768, 768);

  // h2 = rmsnorm(x2, g2)
  rmsnorm_k<<<2048, 256, 0, stream>>>(x2, g2, h2);

  // ffa = gelu(h2 @ Wff1 + b_ff1)   (bf16 out, M=8192, N=3072, K=768)
  gemm_db<128,true,true,false,false><<<64 * 24, 256, 0, stream>>>(h2, Wff1T, b_ff1, nullptr, ffa, 8192, 3072, 768);

  // out = x2 + ffa @ Wff2 + b_ff2   (fp32, M=8192, N=768, K=3072), BM=64
  gemm_db<64,true,false,true,true><<<128 * 6, 256, 0, stream>>>(ffa, Wff2T, b_ff2, x2, out, 8192, 768, 3072);

  // aux scalar
  aux_k<<<1, 64, 0, stream>>>(out + 6291456);
}